// Round 1
// baseline (218.872 us; speedup 1.0000x reference)
//
#include <hip/hip_runtime.h>

typedef __attribute__((ext_vector_type(8))) short bf16x8;
typedef __attribute__((ext_vector_type(4))) float f32x4;
typedef __attribute__((ext_vector_type(4))) unsigned int u32x4;
typedef unsigned short u16;

#define MFMA16(a,b,c) __builtin_amdgcn_mfma_f32_16x16x32_bf16(a,b,c,0,0,0)

// ---------- f32 -> (bf16 hi | bf16 lo) split helpers ----------
// hi = truncate-to-bf16 (top 16 bits); lo = bf16(x - hi)  (exact residual, then truncated)
// reconstruction error ~2^-16 relative -> fp32-class GEMM accuracy with 3 MFMA products.
__device__ __forceinline__ unsigned pack_hilo(float x){
  unsigned u = __float_as_uint(x);
  unsigned hif = u & 0xFFFF0000u;
  float rest = x - __uint_as_float(hif);
  unsigned lo = __float_as_uint(rest) >> 16;
  return hif | lo;
}
__device__ __forceinline__ void split_f32(float x, u16 &hi, u16 &lo){
  unsigned u = __float_as_uint(x);
  unsigned hif = u & 0xFFFF0000u;
  float rest = x - __uint_as_float(hif);
  hi = (u16)(u >> 16);
  lo = (u16)(__float_as_uint(rest) >> 16);
}
__device__ __forceinline__ bf16x8 make_hi(u32x4 a, u32x4 b){
  union { unsigned u[4]; bf16x8 v; } r;
  r.u[0] = (a.x>>16) | (a.y & 0xFFFF0000u);
  r.u[1] = (a.z>>16) | (a.w & 0xFFFF0000u);
  r.u[2] = (b.x>>16) | (b.y & 0xFFFF0000u);
  r.u[3] = (b.z>>16) | (b.w & 0xFFFF0000u);
  return r.v;
}
__device__ __forceinline__ bf16x8 make_lo(u32x4 a, u32x4 b){
  union { unsigned u[4]; bf16x8 v; } r;
  r.u[0] = (a.x & 0xFFFFu) | (a.y << 16);
  r.u[1] = (a.z & 0xFFFFu) | (a.w << 16);
  r.u[2] = (b.x & 0xFFFFu) | (b.y << 16);
  r.u[3] = (b.z & 0xFFFFu) | (b.w << 16);
  return r.v;
}

// XOR swizzle on word index: spreads rows across bank groups (G4 fix for [64][128] tiles)
__device__ __forceinline__ int swz(int row, int col){ return row*128 + (col ^ ((row&7)<<2)); }

// ---------- GEMM phases (16x16x32 bf16 MFMA, bf16x3 split) ----------
// A-tile: LDS packed u32 [64 rows][128 cols], swizzled. W planes: global row-major [128 n][128 k] bf16.
// Wave `wid` owns n-range [wid*32, wid*32+32). acc[m][n]: s = m*16 + (lane>>4)*4 + r, col = n*16 + (lane&15).
__device__ __forceinline__ void gemm_dual(const unsigned* __restrict__ lds,
    const u16* __restrict__ wa_hi, const u16* __restrict__ wa_lo,
    const u16* __restrict__ wb_hi, const u16* __restrict__ wb_lo,
    f32x4 acc1[4][2], f32x4 acc2[4][2], int wid, int lane)
{
  const int lg = lane>>4, li = lane&15;
  #pragma unroll
  for (int k=0;k<4;k++){
    bf16x8 wah[2], wal[2], wbh[2], wbl[2];
    #pragma unroll
    for (int n=0;n<2;n++){
      int off = (wid*32 + n*16 + li)*128 + k*32 + lg*8;
      wah[n] = *(const bf16x8*)(wa_hi + off);
      wal[n] = *(const bf16x8*)(wa_lo + off);
      wbh[n] = *(const bf16x8*)(wb_hi + off);
      wbl[n] = *(const bf16x8*)(wb_lo + off);
    }
    #pragma unroll
    for (int m=0;m<4;m++){
      int arow = m*16 + li;
      int acol = k*32 + lg*8;
      u32x4 p0 = *(const u32x4*)&lds[swz(arow, acol)];
      u32x4 p1 = *(const u32x4*)&lds[swz(arow, acol+4)];
      bf16x8 ah = make_hi(p0,p1), al = make_lo(p0,p1);
      #pragma unroll
      for (int n=0;n<2;n++){
        acc1[m][n] = MFMA16(ah, wah[n], acc1[m][n]);
        acc1[m][n] = MFMA16(al, wah[n], acc1[m][n]);
        acc1[m][n] = MFMA16(ah, wal[n], acc1[m][n]);
        acc2[m][n] = MFMA16(ah, wbh[n], acc2[m][n]);
        acc2[m][n] = MFMA16(al, wbh[n], acc2[m][n]);
        acc2[m][n] = MFMA16(ah, wbl[n], acc2[m][n]);
      }
    }
  }
}

__device__ __forceinline__ void gemm_one(const unsigned* __restrict__ lds,
    const u16* __restrict__ w_hi, const u16* __restrict__ w_lo,
    f32x4 acc[4][2], int wid, int lane)
{
  const int lg = lane>>4, li = lane&15;
  #pragma unroll
  for (int k=0;k<4;k++){
    bf16x8 wh[2], wl[2];
    #pragma unroll
    for (int n=0;n<2;n++){
      int off = (wid*32 + n*16 + li)*128 + k*32 + lg*8;
      wh[n] = *(const bf16x8*)(w_hi + off);
      wl[n] = *(const bf16x8*)(w_lo + off);
    }
    #pragma unroll
    for (int m=0;m<4;m++){
      int arow = m*16 + li;
      int acol = k*32 + lg*8;
      u32x4 p0 = *(const u32x4*)&lds[swz(arow, acol)];
      u32x4 p1 = *(const u32x4*)&lds[swz(arow, acol+4)];
      bf16x8 ah = make_hi(p0,p1), al = make_lo(p0,p1);
      #pragma unroll
      for (int n=0;n<2;n++){
        acc[m][n] = MFMA16(ah, wh[n], acc[m][n]);
        acc[m][n] = MFMA16(al, wh[n], acc[m][n]);
        acc[m][n] = MFMA16(ah, wl[n], acc[m][n]);
      }
    }
  }
}

// ---------- prep: c vectors, folded Wc = hw@wv, bc = hw@bv+hb, W2 split planes ----------
__global__ __launch_bounds__(128) void prep_kernel(
    const float* __restrict__ v1, const float* __restrict__ v2,
    const float* __restrict__ mt_w1, const float* __restrict__ mt_b1,
    const float* __restrict__ mt_w2, const float* __restrict__ mt_b2,
    const float* __restrict__ mt_wv, const float* __restrict__ mt_bv,
    const float* __restrict__ mts_w1, const float* __restrict__ mts_b1,
    const float* __restrict__ mts_w2, const float* __restrict__ mts_b2,
    const float* __restrict__ mts_wv, const float* __restrict__ mts_bv,
    const float* __restrict__ ht_w, const float* __restrict__ ht_b,
    const float* __restrict__ hts_w, const float* __restrict__ hts_b,
    u16* __restrict__ w2a_hi, u16* __restrict__ w2a_lo,
    u16* __restrict__ w2b_hi, u16* __restrict__ w2b_lo,
    u16* __restrict__ wc1_hi, u16* __restrict__ wc1_lo,
    u16* __restrict__ wc2_hi, u16* __restrict__ wc2_lo,
    float* __restrict__ c1, float* __restrict__ c2,
    float* __restrict__ bc1, float* __restrict__ bc2)
{
  const int blk = blockIdx.x;
  const int t = threadIdx.x;   // 128 threads
  if (blk < 128) {
    // c rows: c[b][d] = sum_k w1[d][k]*x[b][k] + b1[d] - b2[d]
    const bool second = blk >= 64;
    const int b = blk & 63;
    const float* x  = second ? v1 : v2;
    const float* w1 = second ? mts_w1 : mt_w1;
    const float* b1 = second ? mts_b1 : mt_b1;
    const float* b2 = second ? mts_b2 : mt_b2;
    float* c = second ? c2 : c1;
    __shared__ float xr[128];
    xr[t] = x[b*128 + t];
    __syncthreads();
    float s = 0.f;
    #pragma unroll 8
    for (int k=0;k<128;k++) s += w1[t*128 + k] * xr[k];
    c[b*128 + t] = s + b1[t] - b2[t];
  } else if (blk < 384) {
    // Wc row e: Wc[e][d] = sum_k hw[e][k]*wv[k][d];  bc[e] = sum_k hw[e][k]*bv[k] + hb[e]
    const bool second = blk >= 256;
    const int e = blk - (second ? 256 : 128);
    const float* hw = second ? hts_w : ht_w;
    const float* wv = second ? mts_wv : mt_wv;
    const float* bv = second ? mts_bv : mt_bv;
    const float* hb = second ? hts_b : ht_b;
    u16* whi = second ? wc2_hi : wc1_hi;
    u16* wlo = second ? wc2_lo : wc1_lo;
    float* bcp = second ? bc2 : bc1;
    float s = 0.f;
    #pragma unroll 8
    for (int k=0;k<128;k++) s += hw[e*128 + k] * wv[k*128 + t];
    u16 hi, lo; split_f32(s, hi, lo);
    whi[e*128 + t] = hi; wlo[e*128 + t] = lo;
    __shared__ float red[128];
    red[t] = hw[e*128 + t] * bv[t];
    __syncthreads();
    for (int off=64; off>0; off>>=1){ if (t<off) red[t] += red[t+off]; __syncthreads(); }
    if (t==0) bcp[e] = red[0] + hb[e];
  } else {
    // W2 split: 128 blocks x 128 threads = 16384 elems, both matrices
    const int i = (blk-384)*128 + t;
    u16 hi, lo;
    split_f32(mt_w2[i], hi, lo);  w2a_hi[i] = hi; w2a_lo[i] = lo;
    split_f32(mts_w2[i], hi, lo); w2b_hi[i] = hi; w2b_lo[i] = lo;
  }
}

// ---------- main: per (b, 64-s tile): gather -> GEMM1(x2) -> relu -> GEMM2(x2) -> score ----------
__global__ __launch_bounds__(256) void main_kernel(
    const float* __restrict__ mem, const int* __restrict__ idx,
    const u16* __restrict__ w2a_hi, const u16* __restrict__ w2a_lo,
    const u16* __restrict__ w2b_hi, const u16* __restrict__ w2b_lo,
    const u16* __restrict__ wc1_hi, const u16* __restrict__ wc1_lo,
    const u16* __restrict__ wc2_hi, const u16* __restrict__ wc2_lo,
    const float* __restrict__ c1, const float* __restrict__ c2,
    const float* __restrict__ bc1, const float* __restrict__ bc2,
    float* __restrict__ out)
{
  __shared__ unsigned ldsA[64*128];   // 32KB packed hi|lo
  __shared__ unsigned ldsB[64*128];   // 32KB
  __shared__ float part[4][64][3];    // 3KB cross-wave score partials

  const int tid = threadIdx.x;
  const int wid = tid >> 6;
  const int lane = tid & 63;
  const int lg = lane >> 4, li = lane & 15;
  const int stile = blockIdx.x;   // 0..63
  const int b = blockIdx.y;       // 0..63
  const int s0 = stile * 64;

  // phase 0: stage gathered memory rows, split to packed hi|lo
  {
    const int row = tid >> 2;
    const int q = tid & 3;
    const int ridx = idx[b*4096 + s0 + row];
    const float4* src = (const float4*)(mem + (size_t)ridx*128 + q*32);
    #pragma unroll
    for (int i=0;i<8;i++){
      float4 f = src[i];
      u32x4 p;
      p.x = pack_hilo(f.x); p.y = pack_hilo(f.y); p.z = pack_hilo(f.z); p.w = pack_hilo(f.w);
      *(u32x4*)&ldsA[swz(row, q*32 + i*4)] = p;
    }
  }
  __syncthreads();

  f32x4 acc1[4][2], acc2[4][2];
  #pragma unroll
  for (int m=0;m<4;m++) for (int n=0;n<2;n++){ acc1[m][n] = (f32x4)(0.f); acc2[m][n] = (f32x4)(0.f); }

  // GEMM1 both branches, shared A-fragments: T = Mrow @ W2^T
  gemm_dual(ldsA, w2a_hi, w2a_lo, w2b_hi, w2b_lo, acc1, acc2, wid, lane);

  // pre1 = relu(c1 - T1) -> ldsB (packed)
  #pragma unroll
  for (int n=0;n<2;n++){
    float ce = c1[b*128 + wid*32 + n*16 + li];
    #pragma unroll
    for (int m=0;m<4;m++)
      #pragma unroll
      for (int r=0;r<4;r++){
        float p = fmaxf(ce - acc1[m][n][r], 0.f);
        ldsB[swz(m*16 + lg*4 + r, wid*32 + n*16 + li)] = pack_hilo(p);
      }
  }
  __syncthreads();   // all GEMM1 reads of ldsA done; pre1 visible
  // pre2 = relu(c2 - T2) -> ldsA (reuse)
  #pragma unroll
  for (int n=0;n<2;n++){
    float ce = c2[b*128 + wid*32 + n*16 + li];
    #pragma unroll
    for (int m=0;m<4;m++)
      #pragma unroll
      for (int r=0;r<4;r++){
        float p = fmaxf(ce - acc2[m][n][r], 0.f);
        ldsA[swz(m*16 + lg*4 + r, wid*32 + n*16 + li)] = pack_hilo(p);
      }
  }
  __syncthreads();

  #pragma unroll
  for (int m=0;m<4;m++) for (int n=0;n<2;n++){ acc1[m][n] = (f32x4)(0.f); acc2[m][n] = (f32x4)(0.f); }
  gemm_one(ldsB, wc1_hi, wc1_lo, acc1, wid, lane);   // H1 = pre1 @ Wc1^T
  gemm_one(ldsA, wc2_hi, wc2_lo, acc2, wid, lane);   // H2 = pre2 @ Wc2^T

  // score reduction: h = acc + bc; need sum_e h1*h2, h1^2, h2^2
  float b1v[2], b2v[2];
  #pragma unroll
  for (int n=0;n<2;n++){
    b1v[n] = bc1[wid*32 + n*16 + li];
    b2v[n] = bc2[wid*32 + n*16 + li];
  }
  #pragma unroll
  for (int m=0;m<4;m++){
    #pragma unroll
    for (int r=0;r<4;r++){
      float p11=0.f, p22=0.f, p12=0.f;
      #pragma unroll
      for (int n=0;n<2;n++){
        float h1 = acc1[m][n][r] + b1v[n];
        float h2 = acc2[m][n][r] + b2v[n];
        p11 += h1*h1; p22 += h2*h2; p12 += h1*h2;
      }
      #pragma unroll
      for (int off=1; off<16; off<<=1){
        p11 += __shfl_xor(p11, off, 64);
        p22 += __shfl_xor(p22, off, 64);
        p12 += __shfl_xor(p12, off, 64);
      }
      if (li == 0){
        int s = m*16 + lg*4 + r;
        part[wid][s][0] = p11; part[wid][s][1] = p22; part[wid][s][2] = p12;
      }
    }
  }
  __syncthreads();
  if (tid < 64){
    float S11 = part[0][tid][0] + part[1][tid][0] + part[2][tid][0] + part[3][tid][0];
    float S22 = part[0][tid][1] + part[1][tid][1] + part[2][tid][1] + part[3][tid][1];
    float S12 = part[0][tid][2] + part[1][tid][2] + part[2][tid][2] + part[3][tid][2];
    float dot = S12 / sqrtf(S11 * S22);
    float score = expf((dot - 1.0f) * (1.0f/0.07f));
    out[(size_t)(s0 + tid)*64 + b] = score;
  }
}

// ---------- new_memory: copy then momentum-update rows y (last-wins on duplicates) ----------
__global__ __launch_bounds__(256) void copy_kernel(const float4* __restrict__ src,
                                                   float4* __restrict__ dst, int n4)
{
  int i = blockIdx.x*blockDim.x + threadIdx.x;
  int stride = gridDim.x*blockDim.x;
  for (; i < n4; i += stride) dst[i] = src[i];
}

__global__ __launch_bounds__(128) void update_kernel(const float* __restrict__ mem,
    const float* __restrict__ v2, const int* __restrict__ y, float* __restrict__ outmem)
{
  const int b = blockIdx.x;
  const int t = threadIdx.x;   // 128 threads
  const int row = y[b];
  for (int b2=b+1; b2<64; ++b2) if (y[b2] == row) return;   // later duplicate wins
  float ab = 0.5f*mem[(size_t)row*128 + t] + 0.5f*v2[b*128 + t];
  __shared__ float red[2];
  float s = ab*ab;
  #pragma unroll
  for (int off=1; off<64; off<<=1) s += __shfl_xor(s, off, 64);
  if ((t & 63) == 0) red[t>>6] = s;
  __syncthreads();
  float tot = red[0] + red[1];
  outmem[(size_t)row*128 + t] = ab / sqrtf(tot);
}

extern "C" void kernel_launch(void* const* d_in, const int* in_sizes, int n_in,
                              void* d_out, int out_size, void* d_ws, size_t ws_size,
                              hipStream_t stream) {
  (void)in_sizes; (void)n_in; (void)out_size; (void)ws_size;
  const float* v1      = (const float*)d_in[0];
  const float* v2      = (const float*)d_in[1];
  const float* mem     = (const float*)d_in[2];
  const float* mt_w1   = (const float*)d_in[3];
  const float* mt_b1   = (const float*)d_in[4];
  const float* mt_w2   = (const float*)d_in[5];
  const float* mt_b2   = (const float*)d_in[6];
  const float* mt_wv   = (const float*)d_in[7];
  const float* mt_bv   = (const float*)d_in[8];
  const float* mts_w1  = (const float*)d_in[9];
  const float* mts_b1  = (const float*)d_in[10];
  const float* mts_w2  = (const float*)d_in[11];
  const float* mts_b2  = (const float*)d_in[12];
  const float* mts_wv  = (const float*)d_in[13];
  const float* mts_bv  = (const float*)d_in[14];
  const float* ht_w    = (const float*)d_in[15];
  const float* ht_b    = (const float*)d_in[16];
  const float* hts_w   = (const float*)d_in[17];
  const float* hts_b   = (const float*)d_in[18];
  const int*   y       = (const int*)d_in[19];
  const int*   idx     = (const int*)d_in[20];
  float* out = (float*)d_out;
  char* ws = (char*)d_ws;

  u16* w2a_hi = (u16*)(ws + 0);
  u16* w2a_lo = (u16*)(ws + 32768);
  u16* w2b_hi = (u16*)(ws + 65536);
  u16* w2b_lo = (u16*)(ws + 98304);
  u16* wc1_hi = (u16*)(ws + 131072);
  u16* wc1_lo = (u16*)(ws + 163840);
  u16* wc2_hi = (u16*)(ws + 196608);
  u16* wc2_lo = (u16*)(ws + 229376);
  float* c1   = (float*)(ws + 262144);
  float* c2   = (float*)(ws + 294912);
  float* bc1  = (float*)(ws + 327680);
  float* bc2  = (float*)(ws + 328192);

  prep_kernel<<<512, 128, 0, stream>>>(v1, v2,
      mt_w1, mt_b1, mt_w2, mt_b2, mt_wv, mt_bv,
      mts_w1, mts_b1, mts_w2, mts_b2, mts_wv, mts_bv,
      ht_w, ht_b, hts_w, hts_b,
      w2a_hi, w2a_lo, w2b_hi, w2b_lo, wc1_hi, wc1_lo, wc2_hi, wc2_lo,
      c1, c2, bc1, bc2);

  main_kernel<<<dim3(64, 64), 256, 0, stream>>>(mem, idx,
      w2a_hi, w2a_lo, w2b_hi, w2b_lo, wc1_hi, wc1_lo, wc2_hi, wc2_lo,
      c1, c2, bc1, bc2, out);

  // new_memory output region starts at 64*4096 floats
  float* outmem = out + 262144;
  copy_kernel<<<2048, 256, 0, stream>>>((const float4*)mem, (float4*)outmem, 3200000);
  update_kernel<<<64, 128, 0, stream>>>(mem, v2, y, outmem);
}

// Round 2
// 188.858 us; speedup vs baseline: 1.1589x; 1.1589x over previous
//
#include <hip/hip_runtime.h>

typedef __attribute__((ext_vector_type(8))) short bf16x8;
typedef __attribute__((ext_vector_type(8))) unsigned short ushort8;
typedef __attribute__((ext_vector_type(4))) float f32x4;
typedef unsigned short u16;

#define MFMA16(a,b,c) __builtin_amdgcn_mfma_f32_16x16x32_bf16(a,b,c,0,0,0)

// ---------- f32 -> (bf16 hi, bf16 lo) split ----------
// hi = truncate-to-bf16; lo = bf16(x - hi). hi*B + lo*B at fp32 accum ~ fp32-class accuracy.
__device__ __forceinline__ void split_f32(float x, u16 &hi, u16 &lo){
  unsigned u = __float_as_uint(x);
  unsigned hif = u & 0xFFFF0000u;
  float rest = x - __uint_as_float(hif);
  hi = (u16)(u >> 16);
  lo = (u16)(__float_as_uint(rest) >> 16);
}

// LDS plane element index: [64 rows][128 cols] u16, 8-col chunks XOR-swizzled by row.
// Staging stores (4 lanes/row at q*32) and GEMM reads (chunk-uniform) both land <=2-way.
__device__ __forceinline__ int swzE(int row, int col){
  int c = (col >> 3) ^ (row & 7);
  return row*128 + c*8 + (col & 7);
}

// ---------- GEMM phases (16x16x32 bf16 MFMA, bf16x3 split) ----------
// A: LDS hi/lo planes. W: global interleaved [row][16 chunks][8 hi | 8 lo] u16 (row stride 256).
// Wave wid owns n-cols [wid*32, wid*32+32). acc[m][n][r]: s = m*16+(lane>>4)*4+r, e = n*16+(lane&15).
__device__ __forceinline__ void gemm_dual(const u16* __restrict__ ldsHi, const u16* __restrict__ ldsLo,
    const u16* __restrict__ wa, const u16* __restrict__ wb,
    f32x4 acc1[4][2], f32x4 acc2[4][2], int wid, int lane)
{
  const int lg = lane>>4, li = lane&15;
  #pragma unroll
  for (int k=0;k<4;k++){
    bf16x8 wah[2], wal[2], wbh[2], wbl[2];
    #pragma unroll
    for (int n=0;n<2;n++){
      int off = (wid*32 + n*16 + li)*256 + (k*4+lg)*16;
      wah[n] = *(const bf16x8*)(wa + off);
      wal[n] = *(const bf16x8*)(wa + off + 8);
      wbh[n] = *(const bf16x8*)(wb + off);
      wbl[n] = *(const bf16x8*)(wb + off + 8);
    }
    #pragma unroll
    for (int m=0;m<4;m++){
      int arow = m*16 + li;
      int base = arow*128 + (((k*4+lg) ^ (arow&7))<<3);
      bf16x8 ah = *(const bf16x8*)(ldsHi + base);
      bf16x8 al = *(const bf16x8*)(ldsLo + base);
      #pragma unroll
      for (int n=0;n<2;n++){
        acc1[m][n] = MFMA16(ah, wah[n], acc1[m][n]);
        acc1[m][n] = MFMA16(al, wah[n], acc1[m][n]);
        acc1[m][n] = MFMA16(ah, wal[n], acc1[m][n]);
        acc2[m][n] = MFMA16(ah, wbh[n], acc2[m][n]);
        acc2[m][n] = MFMA16(al, wbh[n], acc2[m][n]);
        acc2[m][n] = MFMA16(ah, wbl[n], acc2[m][n]);
      }
    }
  }
}

__device__ __forceinline__ void gemm_one(const u16* __restrict__ ldsHi, const u16* __restrict__ ldsLo,
    const u16* __restrict__ w, f32x4 acc[4][2], int wid, int lane)
{
  const int lg = lane>>4, li = lane&15;
  #pragma unroll
  for (int k=0;k<4;k++){
    bf16x8 wh[2], wl[2];
    #pragma unroll
    for (int n=0;n<2;n++){
      int off = (wid*32 + n*16 + li)*256 + (k*4+lg)*16;
      wh[n] = *(const bf16x8*)(w + off);
      wl[n] = *(const bf16x8*)(w + off + 8);
    }
    #pragma unroll
    for (int m=0;m<4;m++){
      int arow = m*16 + li;
      int base = arow*128 + (((k*4+lg) ^ (arow&7))<<3);
      bf16x8 ah = *(const bf16x8*)(ldsHi + base);
      bf16x8 al = *(const bf16x8*)(ldsLo + base);
      #pragma unroll
      for (int n=0;n<2;n++){
        acc[m][n] = MFMA16(ah, wh[n], acc[m][n]);
        acc[m][n] = MFMA16(al, wh[n], acc[m][n]);
        acc[m][n] = MFMA16(ah, wl[n], acc[m][n]);
      }
    }
  }
}

// ---------- prep: c vectors, folded Wc = hw@wv, bc = hw@bv+hb, W2 split+interleave ----------
__global__ __launch_bounds__(128) void prep_kernel(
    const float* __restrict__ v1, const float* __restrict__ v2,
    const float* __restrict__ mt_w1, const float* __restrict__ mt_b1,
    const float* __restrict__ mt_w2, const float* __restrict__ mt_b2,
    const float* __restrict__ mt_wv, const float* __restrict__ mt_bv,
    const float* __restrict__ mts_w1, const float* __restrict__ mts_b1,
    const float* __restrict__ mts_w2, const float* __restrict__ mts_b2,
    const float* __restrict__ mts_wv, const float* __restrict__ mts_bv,
    const float* __restrict__ ht_w, const float* __restrict__ ht_b,
    const float* __restrict__ hts_w, const float* __restrict__ hts_b,
    u16* __restrict__ w2a, u16* __restrict__ w2b,
    u16* __restrict__ wc1, u16* __restrict__ wc2,
    float* __restrict__ c1, float* __restrict__ c2,
    float* __restrict__ bc1, float* __restrict__ bc2)
{
  const int blk = blockIdx.x;
  const int t = threadIdx.x;   // 128 threads
  if (blk < 128) {
    // c[b][d] = sum_k w1[d][k]*x[b][k] + b1[d] - b2[d]
    const bool second = blk >= 64;
    const int b = blk & 63;
    const float* x  = second ? v1 : v2;
    const float* w1 = second ? mts_w1 : mt_w1;
    const float* b1 = second ? mts_b1 : mt_b1;
    const float* b2 = second ? mts_b2 : mt_b2;
    float* c = second ? c2 : c1;
    __shared__ float xr[128];
    xr[t] = x[b*128 + t];
    __syncthreads();
    float s = 0.f;
    #pragma unroll 8
    for (int k=0;k<128;k++) s += w1[t*128 + k] * xr[k];
    c[b*128 + t] = s + b1[t] - b2[t];
  } else if (blk < 384) {
    // Wc row e: Wc[e][d] = sum_k hw[e][k]*wv[k][d];  bc[e] = hw[e]·bv + hb[e]
    const bool second = blk >= 256;
    const int e = blk - (second ? 256 : 128);
    const float* hw = second ? hts_w : ht_w;
    const float* wv = second ? mts_wv : mt_wv;
    const float* bv = second ? mts_bv : mt_bv;
    const float* hb = second ? hts_b : ht_b;
    u16* wc = second ? wc2 : wc1;
    float* bcp = second ? bc2 : bc1;
    float s = 0.f;
    #pragma unroll 8
    for (int k=0;k<128;k++) s += hw[e*128 + k] * wv[k*128 + t];
    u16 hi, lo; split_f32(s, hi, lo);
    int oi = e*256 + ((t>>3)<<4) + (t&7);
    wc[oi] = hi; wc[oi+8] = lo;
    __shared__ float red[128];
    red[t] = hw[e*128 + t] * bv[t];
    __syncthreads();
    for (int off=64; off>0; off>>=1){ if (t<off) red[t] += red[t+off]; __syncthreads(); }
    if (t==0) bcp[e] = red[0] + hb[e];
  } else {
    // W2 split + interleave: 128 blocks x 128 threads = 16384 elems, both matrices
    const int i = (blk-384)*128 + t;
    const int r = i >> 7, col = i & 127;
    const int oi = r*256 + ((col>>3)<<4) + (col&7);
    u16 hi, lo;
    split_f32(mt_w2[i], hi, lo);  w2a[oi] = hi; w2a[oi+8] = lo;
    split_f32(mts_w2[i], hi, lo); w2b[oi] = hi; w2b[oi+8] = lo;
  }
}

// ---------- main: per (b, 64-s tile): gather -> GEMM1(dual) -> pre1/h1 -> pre2/h2 -> score ----------
__global__ __launch_bounds__(256, 4) void main_kernel(
    const float* __restrict__ mem, const int* __restrict__ idx,
    const u16* __restrict__ w2a, const u16* __restrict__ w2b,
    const u16* __restrict__ wc1, const u16* __restrict__ wc2,
    const float* __restrict__ c1, const float* __restrict__ c2,
    const float* __restrict__ bc1, const float* __restrict__ bc2,
    float* __restrict__ out)
{
  __shared__ u16 ldsHi[64*128];      // 16KB
  __shared__ u16 ldsLo[64*128];      // 16KB
  __shared__ float part[4][64][3];   // 3KB

  const int tid = threadIdx.x;
  const int wid = tid >> 6;
  const int lane = tid & 63;
  const int lg = lane >> 4, li = lane & 15;
  const int stile = blockIdx.x;   // 0..63
  const int b = blockIdx.y;       // 0..63
  const int s0 = stile * 64;

  // phase 0: stage gathered memory rows -> hi/lo planes
  {
    const int row = tid >> 2;
    const int q = tid & 3;
    const int ridx = idx[b*4096 + s0 + row];
    const float4* src = (const float4*)(mem + (size_t)ridx*128 + q*32);
    #pragma unroll
    for (int ch=0; ch<4; ch++){
      float4 f0 = src[ch*2], f1 = src[ch*2+1];
      ushort8 hi8, lo8;
      split_f32(f0.x, ((u16*)&hi8)[0], ((u16*)&lo8)[0]);
      split_f32(f0.y, ((u16*)&hi8)[1], ((u16*)&lo8)[1]);
      split_f32(f0.z, ((u16*)&hi8)[2], ((u16*)&lo8)[2]);
      split_f32(f0.w, ((u16*)&hi8)[3], ((u16*)&lo8)[3]);
      split_f32(f1.x, ((u16*)&hi8)[4], ((u16*)&lo8)[4]);
      split_f32(f1.y, ((u16*)&hi8)[5], ((u16*)&lo8)[5]);
      split_f32(f1.z, ((u16*)&hi8)[6], ((u16*)&lo8)[6]);
      split_f32(f1.w, ((u16*)&hi8)[7], ((u16*)&lo8)[7]);
      int base = swzE(row, q*32 + ch*8);
      *(ushort8*)&ldsHi[base] = hi8;
      *(ushort8*)&ldsLo[base] = lo8;
    }
  }
  __syncthreads();

  f32x4 acc1[4][2], acc2[4][2];
  #pragma unroll
  for (int m=0;m<4;m++) for (int n=0;n<2;n++){ acc1[m][n] = (f32x4)(0.f); acc2[m][n] = (f32x4)(0.f); }

  // GEMM1 both branches, shared A-fragments: T = Mrow @ W2^T
  gemm_dual(ldsHi, ldsLo, w2a, w2b, acc1, acc2, wid, lane);
  __syncthreads();   // all reads of staged rows done

  // pre1 = relu(c1 - T1) -> lds planes (overwrite)
  #pragma unroll
  for (int n=0;n<2;n++){
    float ce = c1[b*128 + wid*32 + n*16 + li];
    #pragma unroll
    for (int m=0;m<4;m++)
      #pragma unroll
      for (int r=0;r<4;r++){
        float p = fmaxf(ce - acc1[m][n][r], 0.f);
        int ii = swzE(m*16 + lg*4 + r, wid*32 + n*16 + li);
        u16 hi, lo; split_f32(p, hi, lo);
        ldsHi[ii] = hi; ldsLo[ii] = lo;
      }
  }
  __syncthreads();

  #pragma unroll
  for (int m=0;m<4;m++) for (int n=0;n<2;n++) acc1[m][n] = (f32x4)(0.f);
  gemm_one(ldsHi, ldsLo, wc1, acc1, wid, lane);   // H1 = pre1 @ Wc1^T
  __syncthreads();   // reads of pre1 done

  // pre2 = relu(c2 - T2) -> lds planes (T2 parked in acc2)
  #pragma unroll
  for (int n=0;n<2;n++){
    float ce = c2[b*128 + wid*32 + n*16 + li];
    #pragma unroll
    for (int m=0;m<4;m++)
      #pragma unroll
      for (int r=0;r<4;r++){
        float p = fmaxf(ce - acc2[m][n][r], 0.f);
        int ii = swzE(m*16 + lg*4 + r, wid*32 + n*16 + li);
        u16 hi, lo; split_f32(p, hi, lo);
        ldsHi[ii] = hi; ldsLo[ii] = lo;
      }
  }
  __syncthreads();

  #pragma unroll
  for (int m=0;m<4;m++) for (int n=0;n<2;n++) acc2[m][n] = (f32x4)(0.f);
  gemm_one(ldsHi, ldsLo, wc2, acc2, wid, lane);   // H2 = pre2 @ Wc2^T

  // score: h = acc + bc; need sum_e h1*h2, h1^2, h2^2
  float b1v[2], b2v[2];
  #pragma unroll
  for (int n=0;n<2;n++){
    b1v[n] = bc1[wid*32 + n*16 + li];
    b2v[n] = bc2[wid*32 + n*16 + li];
  }
  #pragma unroll
  for (int m=0;m<4;m++){
    #pragma unroll
    for (int r=0;r<4;r++){
      float p11=0.f, p22=0.f, p12=0.f;
      #pragma unroll
      for (int n=0;n<2;n++){
        float h1 = acc1[m][n][r] + b1v[n];
        float h2 = acc2[m][n][r] + b2v[n];
        p11 += h1*h1; p22 += h2*h2; p12 += h1*h2;
      }
      #pragma unroll
      for (int off=1; off<16; off<<=1){
        p11 += __shfl_xor(p11, off, 64);
        p22 += __shfl_xor(p22, off, 64);
        p12 += __shfl_xor(p12, off, 64);
      }
      if (li == 0){
        int s = m*16 + lg*4 + r;
        part[wid][s][0] = p11; part[wid][s][1] = p22; part[wid][s][2] = p12;
      }
    }
  }
  __syncthreads();
  if (tid < 64){
    float S11 = part[0][tid][0] + part[1][tid][0] + part[2][tid][0] + part[3][tid][0];
    float S22 = part[0][tid][1] + part[1][tid][1] + part[2][tid][1] + part[3][tid][1];
    float S12 = part[0][tid][2] + part[1][tid][2] + part[2][tid][2] + part[3][tid][2];
    float dot = S12 / sqrtf(S11 * S22);
    out[(size_t)(s0 + tid)*64 + b] = expf((dot - 1.0f) * (1.0f/0.07f));
  }
}

// ---------- new_memory: copy then momentum-update rows y (last-wins on duplicates) ----------
__global__ __launch_bounds__(256) void copy_kernel(const float4* __restrict__ src,
                                                   float4* __restrict__ dst, int n4)
{
  int i = blockIdx.x*blockDim.x + threadIdx.x;
  int stride = gridDim.x*blockDim.x;
  for (; i < n4; i += stride) dst[i] = src[i];
}

__global__ __launch_bounds__(128) void update_kernel(const float* __restrict__ mem,
    const float* __restrict__ v2, const int* __restrict__ y, float* __restrict__ outmem)
{
  const int b = blockIdx.x;
  const int t = threadIdx.x;   // 128 threads
  const int row = y[b];
  for (int b2=b+1; b2<64; ++b2) if (y[b2] == row) return;   // later duplicate wins
  float ab = 0.5f*mem[(size_t)row*128 + t] + 0.5f*v2[b*128 + t];
  __shared__ float red[2];
  float s = ab*ab;
  #pragma unroll
  for (int off=1; off<64; off<<=1) s += __shfl_xor(s, off, 64);
  if ((t & 63) == 0) red[t>>6] = s;
  __syncthreads();
  float tot = red[0] + red[1];
  outmem[(size_t)row*128 + t] = ab / sqrtf(tot);
}

extern "C" void kernel_launch(void* const* d_in, const int* in_sizes, int n_in,
                              void* d_out, int out_size, void* d_ws, size_t ws_size,
                              hipStream_t stream) {
  (void)in_sizes; (void)n_in; (void)out_size; (void)ws_size;
  const float* v1      = (const float*)d_in[0];
  const float* v2      = (const float*)d_in[1];
  const float* mem     = (const float*)d_in[2];
  const float* mt_w1   = (const float*)d_in[3];
  const float* mt_b1   = (const float*)d_in[4];
  const float* mt_w2   = (const float*)d_in[5];
  const float* mt_b2   = (const float*)d_in[6];
  const float* mt_wv   = (const float*)d_in[7];
  const float* mt_bv   = (const float*)d_in[8];
  const float* mts_w1  = (const float*)d_in[9];
  const float* mts_b1  = (const float*)d_in[10];
  const float* mts_w2  = (const float*)d_in[11];
  const float* mts_b2  = (const float*)d_in[12];
  const float* mts_wv  = (const float*)d_in[13];
  const float* mts_bv  = (const float*)d_in[14];
  const float* ht_w    = (const float*)d_in[15];
  const float* ht_b    = (const float*)d_in[16];
  const float* hts_w   = (const float*)d_in[17];
  const float* hts_b   = (const float*)d_in[18];
  const int*   y       = (const int*)d_in[19];
  const int*   idx     = (const int*)d_in[20];
  float* out = (float*)d_out;
  char* ws = (char*)d_ws;

  u16* w2a = (u16*)(ws + 0);        // 128*256*2 = 64KB each
  u16* w2b = (u16*)(ws + 65536);
  u16* wc1 = (u16*)(ws + 131072);
  u16* wc2 = (u16*)(ws + 196608);
  float* c1   = (float*)(ws + 262144);
  float* c2   = (float*)(ws + 294912);
  float* bc1  = (float*)(ws + 327680);
  float* bc2  = (float*)(ws + 328192);

  prep_kernel<<<512, 128, 0, stream>>>(v1, v2,
      mt_w1, mt_b1, mt_w2, mt_b2, mt_wv, mt_bv,
      mts_w1, mts_b1, mts_w2, mts_b2, mts_wv, mts_bv,
      ht_w, ht_b, hts_w, hts_b,
      w2a, w2b, wc1, wc2, c1, c2, bc1, bc2);

  main_kernel<<<dim3(64, 64), 256, 0, stream>>>(mem, idx,
      w2a, w2b, wc1, wc2, c1, c2, bc1, bc2, out);

  // new_memory output region starts at 64*4096 floats
  float* outmem = out + 262144;
  copy_kernel<<<2048, 256, 0, stream>>>((const float4*)mem, (float4*)outmem, 3200000);
  update_kernel<<<64, 128, 0, stream>>>(mem, v2, y, outmem);
}

// Round 3
// 178.849 us; speedup vs baseline: 1.2238x; 1.0560x over previous
//
#include <hip/hip_runtime.h>

typedef __attribute__((ext_vector_type(8))) short bf16x8;
typedef __attribute__((ext_vector_type(4))) float f32x4;
typedef __attribute__((ext_vector_type(4))) unsigned short u16x4;
typedef unsigned short u16;
typedef unsigned int u32;

#define MFMA16(a,b,c) __builtin_amdgcn_mfma_f32_16x16x32_bf16(a,b,c,0,0,0)

// ---------- f32 -> (bf16 hi, bf16 lo) split ----------
// hi = truncate-to-bf16; lo = bf16(x - hi). 3-product MFMA ~ fp32-class accuracy.
__device__ __forceinline__ void split_f32(float x, u16 &hi, u16 &lo){
  unsigned u = __float_as_uint(x);
  unsigned hif = u & 0xFFFF0000u;
  float rest = x - __uint_as_float(hif);
  hi = (u16)(u >> 16);
  lo = (u16)(__float_as_uint(rest) >> 16);
}

__device__ __forceinline__ void gload_lds16(const void* g, void* l){
  __builtin_amdgcn_global_load_lds((const __attribute__((address_space(1))) u32*)g,
                                   (__attribute__((address_space(3))) u32*)l, 16, 0, 0);
}

// LDS planes: [64 rows][128 u16]; 16B slot sl stored at slot sl ^ (row&15).
// b64 granule g (4 u16): slot = g>>1, half = g&1.

// ---------- flipped GEMMs: D[d'][s] = sum_d W[d'][d] * M[s][d] ----------
// first operand = W-frag (rows e = wid*32+mm*16+li, chunk k*4+lg, global interleaved 8hi|8lo)
// second = M-frag (rows s = n*16+li from LDS planes)
// acc[mm][n][r]: d' = wid*32+mm*16+lg*4+r, s = n*16+li
__device__ __forceinline__ void gemm_dual_flip(const u16* ldsHi, const u16* ldsLo,
    const u16* __restrict__ wa, const u16* __restrict__ wb,
    f32x4 acc1[2][4], f32x4 acc2[2][4], int wid, int lg, int li)
{
  const int rowbase = (wid*32 + li)*256 + lg*16;  // + mm*4096 + k*64 (+8 for lo)
  bf16x8 pah[2][2], pbh[2][2];
  #pragma unroll
  for (int mm=0;mm<2;mm++){
    pah[0][mm] = *(const bf16x8*)(wa + rowbase + mm*4096);
    pbh[0][mm] = *(const bf16x8*)(wb + rowbase + mm*4096);
  }
  #pragma unroll
  for (int k=0;k<4;k++){
    const int cur = k&1, nxt = cur^1;
    if (k<3){
      #pragma unroll
      for (int mm=0;mm<2;mm++){
        pah[nxt][mm] = *(const bf16x8*)(wa + rowbase + mm*4096 + (k+1)*64);
        pbh[nxt][mm] = *(const bf16x8*)(wb + rowbase + mm*4096 + (k+1)*64);
      }
    }
    bf16x8 pal[2], pbl[2];
    #pragma unroll
    for (int mm=0;mm<2;mm++){
      pal[mm] = *(const bf16x8*)(wa + rowbase + mm*4096 + k*64 + 8);
      pbl[mm] = *(const bf16x8*)(wb + rowbase + mm*4096 + k*64 + 8);
    }
    #pragma unroll
    for (int n=0;n<4;n++){
      const int row = n*16 + li;
      const int a = row*128 + (((k*4+lg) ^ li)<<3);
      bf16x8 bh = *(const bf16x8*)(ldsHi + a);
      bf16x8 bl = *(const bf16x8*)(ldsLo + a);
      #pragma unroll
      for (int mm=0;mm<2;mm++){
        acc1[mm][n] = MFMA16(pah[cur][mm], bh, acc1[mm][n]);
        acc2[mm][n] = MFMA16(pbh[cur][mm], bh, acc2[mm][n]);
        acc1[mm][n] = MFMA16(pah[cur][mm], bl, acc1[mm][n]);
        acc2[mm][n] = MFMA16(pbh[cur][mm], bl, acc2[mm][n]);
        acc1[mm][n] = MFMA16(pal[mm], bh, acc1[mm][n]);
        acc2[mm][n] = MFMA16(pbl[mm], bh, acc2[mm][n]);
      }
    }
  }
}

__device__ __forceinline__ void gemm_one_flip(const u16* ldsHi, const u16* ldsLo,
    const u16* __restrict__ w, f32x4 acc[2][4], int wid, int lg, int li)
{
  const int rowbase = (wid*32 + li)*256 + lg*16;
  bf16x8 ph[2][2];
  #pragma unroll
  for (int mm=0;mm<2;mm++) ph[0][mm] = *(const bf16x8*)(w + rowbase + mm*4096);
  #pragma unroll
  for (int k=0;k<4;k++){
    const int cur = k&1, nxt = cur^1;
    if (k<3){
      #pragma unroll
      for (int mm=0;mm<2;mm++)
        ph[nxt][mm] = *(const bf16x8*)(w + rowbase + mm*4096 + (k+1)*64);
    }
    bf16x8 pl[2];
    #pragma unroll
    for (int mm=0;mm<2;mm++) pl[mm] = *(const bf16x8*)(w + rowbase + mm*4096 + k*64 + 8);
    #pragma unroll
    for (int n=0;n<4;n++){
      const int row = n*16 + li;
      const int a = row*128 + (((k*4+lg) ^ li)<<3);
      bf16x8 bh = *(const bf16x8*)(ldsHi + a);
      bf16x8 bl = *(const bf16x8*)(ldsLo + a);
      #pragma unroll
      for (int mm=0;mm<2;mm++){
        acc[mm][n] = MFMA16(ph[cur][mm], bh, acc[mm][n]);
        acc[mm][n] = MFMA16(ph[cur][mm], bl, acc[mm][n]);
        acc[mm][n] = MFMA16(pl[mm], bh, acc[mm][n]);
      }
    }
  }
}

// pre[s][d'] = relu(c[d'] - T[d'][s]) -> LDS planes, b64 vectorized along d'
__device__ __forceinline__ void write_pre(u16* ldsHi, u16* ldsLo,
    const f32x4 acc[2][4], const float* __restrict__ cvec, int wid, int lg, int li)
{
  #pragma unroll
  for (int mm=0;mm<2;mm++){
    float4 cv = *(const float4*)(cvec + wid*32 + mm*16 + lg*4);
    const int g = wid*8 + mm*4 + lg;
    #pragma unroll
    for (int n=0;n<4;n++){
      const int row = n*16 + li;
      u16x4 h4, l4;
      #pragma unroll
      for (int r=0;r<4;r++){
        float cr = (r==0)?cv.x:(r==1)?cv.y:(r==2)?cv.z:cv.w;
        float p = fmaxf(cr - acc[mm][n][r], 0.f);
        u16 hh, ll; split_f32(p, hh, ll);
        h4[r] = hh; l4[r] = ll;
      }
      const int a = row*128 + (((g>>1) ^ li)<<3) + ((g&1)<<2);
      *(u16x4*)&ldsHi[a] = h4;
      *(u16x4*)&ldsLo[a] = l4;
    }
  }
}

// ---------- prep: c vectors, folded Wc = hw@wv, bc = hw@bv+hb, W2 split+interleave ----------
__global__ __launch_bounds__(128) void prep_kernel(
    const float* __restrict__ v1, const float* __restrict__ v2,
    const float* __restrict__ mt_w1, const float* __restrict__ mt_b1,
    const float* __restrict__ mt_w2, const float* __restrict__ mt_b2,
    const float* __restrict__ mt_wv, const float* __restrict__ mt_bv,
    const float* __restrict__ mts_w1, const float* __restrict__ mts_b1,
    const float* __restrict__ mts_w2, const float* __restrict__ mts_b2,
    const float* __restrict__ mts_wv, const float* __restrict__ mts_bv,
    const float* __restrict__ ht_w, const float* __restrict__ ht_b,
    const float* __restrict__ hts_w, const float* __restrict__ hts_b,
    u16* __restrict__ w2a, u16* __restrict__ w2b,
    u16* __restrict__ wc1, u16* __restrict__ wc2,
    float* __restrict__ c1, float* __restrict__ c2,
    float* __restrict__ bc1, float* __restrict__ bc2)
{
  const int blk = blockIdx.x;
  const int t = threadIdx.x;   // 128 threads
  if (blk < 128) {
    const bool second = blk >= 64;
    const int b = blk & 63;
    const float* x  = second ? v1 : v2;
    const float* w1 = second ? mts_w1 : mt_w1;
    const float* b1 = second ? mts_b1 : mt_b1;
    const float* b2 = second ? mts_b2 : mt_b2;
    float* c = second ? c2 : c1;
    __shared__ float xr[128];
    xr[t] = x[b*128 + t];
    __syncthreads();
    float s = 0.f;
    #pragma unroll 8
    for (int k=0;k<128;k++) s += w1[t*128 + k] * xr[k];
    c[b*128 + t] = s + b1[t] - b2[t];
  } else if (blk < 384) {
    const bool second = blk >= 256;
    const int e = blk - (second ? 256 : 128);
    const float* hw = second ? hts_w : ht_w;
    const float* wv = second ? mts_wv : mt_wv;
    const float* bv = second ? mts_bv : mt_bv;
    const float* hb = second ? hts_b : ht_b;
    u16* wc = second ? wc2 : wc1;
    float* bcp = second ? bc2 : bc1;
    float s = 0.f;
    #pragma unroll 8
    for (int k=0;k<128;k++) s += hw[e*128 + k] * wv[k*128 + t];
    u16 hi, lo; split_f32(s, hi, lo);
    int oi = e*256 + ((t>>3)<<4) + (t&7);
    wc[oi] = hi; wc[oi+8] = lo;
    __shared__ float red[128];
    red[t] = hw[e*128 + t] * bv[t];
    __syncthreads();
    for (int off=64; off>0; off>>=1){ if (t<off) red[t] += red[t+off]; __syncthreads(); }
    if (t==0) bcp[e] = red[0] + hb[e];
  } else {
    const int i = (blk-384)*128 + t;
    const int r = i >> 7, col = i & 127;
    const int oi = r*256 + ((col>>3)<<4) + (col&7);
    u16 hi, lo;
    split_f32(mt_w2[i], hi, lo);  w2a[oi] = hi; w2a[oi+8] = lo;
    split_f32(mts_w2[i], hi, lo); w2b[oi] = hi; w2b[oi+8] = lo;
  }
}

// ---------- main ----------
__global__ __launch_bounds__(256, 4) void main_kernel(
    const u16* __restrict__ mh, const u16* __restrict__ ml,
    const int* __restrict__ idx,
    const u16* __restrict__ w2a, const u16* __restrict__ w2b,
    const u16* __restrict__ wc1, const u16* __restrict__ wc2,
    const float* __restrict__ c1, const float* __restrict__ c2,
    const float* __restrict__ bc1, const float* __restrict__ bc2,
    float* __restrict__ wss)
{
  __shared__ u16 ldsHi[64*128];      // 16KB
  __shared__ u16 ldsLo[64*128];      // 16KB
  __shared__ float part[4][64][3];   // 3KB

  const int tid = threadIdx.x;
  const int wid = tid >> 6;
  const int lane = tid & 63;
  const int lg = lane >> 4, li = lane & 15;
  const int stile = blockIdx.x, b = blockIdx.y;
  const int s0 = stile * 64;

  // stage: wave wid stages rows wid*16..+16 from pre-split planes via global_load_lds
  {
    const int q = lane >> 4;       // sub-row within group of 4
    const int sl = lane & 15;      // dest 16B slot
    #pragma unroll
    for (int i=0;i<4;i++){
      const int rloc = i*4 + q;                          // row&15
      const int row  = wid*16 + rloc;
      const int ridx = idx[b*4096 + s0 + row];
      const int srcslot = sl ^ rloc;
      const size_t soff = (size_t)ridx*128 + srcslot*8;  // u16 units
      gload_lds16(mh + soff, &ldsHi[(wid*16 + i*4)*128]);
      gload_lds16(ml + soff, &ldsLo[(wid*16 + i*4)*128]);
    }
  }
  __syncthreads();

  f32x4 acc1[2][4], acc2[2][4];
  #pragma unroll
  for (int mm=0;mm<2;mm++) for (int n=0;n<4;n++){ acc1[mm][n]=(f32x4)(0.f); acc2[mm][n]=(f32x4)(0.f); }

  gemm_dual_flip(ldsHi, ldsLo, w2a, w2b, acc1, acc2, wid, lg, li);   // T1^T, T2^T
  __syncthreads();                                                   // M reads done

  write_pre(ldsHi, ldsLo, acc1, c1 + b*128, wid, lg, li);            // pre1 -> planes
  __syncthreads();

  f32x4 h1[2][4];
  #pragma unroll
  for (int mm=0;mm<2;mm++) for (int n=0;n<4;n++) h1[mm][n]=(f32x4)(0.f);
  gemm_one_flip(ldsHi, ldsLo, wc1, h1, wid, lg, li);                 // H1^T
  __syncthreads();                                                   // pre1 reads done

  write_pre(ldsHi, ldsLo, acc2, c2 + b*128, wid, lg, li);            // pre2 -> planes
  __syncthreads();

  f32x4 h2[2][4];
  #pragma unroll
  for (int mm=0;mm<2;mm++) for (int n=0;n<4;n++) h2[mm][n]=(f32x4)(0.f);
  gemm_one_flip(ldsHi, ldsLo, wc2, h2, wid, lg, li);                 // H2^T

  // score partials: lane holds h[e'][s], e' = wid*32+mm*16+lg*4+r, s = n*16+li
  float4 b1v[2], b2v[2];
  #pragma unroll
  for (int mm=0;mm<2;mm++){
    b1v[mm] = *(const float4*)(bc1 + wid*32 + mm*16 + lg*4);
    b2v[mm] = *(const float4*)(bc2 + wid*32 + mm*16 + lg*4);
  }
  #pragma unroll
  for (int n=0;n<4;n++){
    float p11=0.f, p22=0.f, p12=0.f;
    #pragma unroll
    for (int mm=0;mm<2;mm++){
      #pragma unroll
      for (int r=0;r<4;r++){
        float bb1 = (r==0)?b1v[mm].x:(r==1)?b1v[mm].y:(r==2)?b1v[mm].z:b1v[mm].w;
        float bb2 = (r==0)?b2v[mm].x:(r==1)?b2v[mm].y:(r==2)?b2v[mm].z:b2v[mm].w;
        float v1h = h1[mm][n][r] + bb1;
        float v2h = h2[mm][n][r] + bb2;
        p11 += v1h*v1h; p22 += v2h*v2h; p12 += v1h*v2h;
      }
    }
    p11 += __shfl_xor(p11, 16, 64); p11 += __shfl_xor(p11, 32, 64);
    p22 += __shfl_xor(p22, 16, 64); p22 += __shfl_xor(p22, 32, 64);
    p12 += __shfl_xor(p12, 16, 64); p12 += __shfl_xor(p12, 32, 64);
    if (lane < 16){
      part[wid][n*16+li][0] = p11;
      part[wid][n*16+li][1] = p22;
      part[wid][n*16+li][2] = p12;
    }
  }
  __syncthreads();
  if (tid < 64){
    float S11 = part[0][tid][0] + part[1][tid][0] + part[2][tid][0] + part[3][tid][0];
    float S22 = part[0][tid][1] + part[1][tid][1] + part[2][tid][1] + part[3][tid][1];
    float S12 = part[0][tid][2] + part[1][tid][2] + part[2][tid][2] + part[3][tid][2];
    float dot = S12 / sqrtf(S11 * S22);
    wss[(size_t)b*4096 + s0 + tid] = expf((dot - 1.0f) * (1.0f/0.07f));
  }
}

// ---------- split (+ optional copy): bank -> hi/lo planes ----------
__global__ __launch_bounds__(256) void split_copy_kernel(const float4* __restrict__ src,
    float4* __restrict__ dst, u16x4* __restrict__ mh, u16x4* __restrict__ ml,
    int n4, int docopy)
{
  int i = blockIdx.x*256 + threadIdx.x;
  const int stride = gridDim.x*256;
  for (; i < n4; i += stride){
    float4 f = src[i];
    if (docopy) dst[i] = f;
    u16x4 h, l; u16 hh, ll;
    split_f32(f.x, hh, ll); h[0]=hh; l[0]=ll;
    split_f32(f.y, hh, ll); h[1]=hh; l[1]=ll;
    split_f32(f.z, hh, ll); h[2]=hh; l[2]=ll;
    split_f32(f.w, hh, ll); h[3]=hh; l[3]=ll;
    mh[i] = h; ml[i] = l;
  }
}

__global__ __launch_bounds__(256) void copy_kernel(const float4* __restrict__ src,
                                                   float4* __restrict__ dst, int n4)
{
  int i = blockIdx.x*256 + threadIdx.x;
  const int stride = gridDim.x*256;
  for (; i < n4; i += stride) dst[i] = src[i];
}

__global__ __launch_bounds__(128) void update_kernel(const float* __restrict__ mem,
    const float* __restrict__ v2, const int* __restrict__ y, float* __restrict__ outmem)
{
  const int b = blockIdx.x;
  const int t = threadIdx.x;
  const int row = y[b];
  for (int b2=b+1; b2<64; ++b2) if (y[b2] == row) return;   // later duplicate wins
  float ab = 0.5f*mem[(size_t)row*128 + t] + 0.5f*v2[b*128 + t];
  __shared__ float red[2];
  float s = ab*ab;
  #pragma unroll
  for (int off=1; off<64; off<<=1) s += __shfl_xor(s, off, 64);
  if ((t & 63) == 0) red[t>>6] = s;
  __syncthreads();
  float tot = red[0] + red[1];
  outmem[(size_t)row*128 + t] = ab / sqrtf(tot);
}

// scores ws[b][s] -> out[s][b]
__global__ __launch_bounds__(256) void transpose_kernel(const float* __restrict__ wss,
                                                        float* __restrict__ out)
{
  __shared__ float tile[64][65];
  const int t = blockIdx.x;
  const int c = threadIdx.x & 63;
  const int r4 = threadIdx.x >> 6;
  #pragma unroll
  for (int i=0;i<16;i++){
    int bb = i*4 + r4;
    tile[bb][c] = wss[(size_t)bb*4096 + t*64 + c];
  }
  __syncthreads();
  #pragma unroll
  for (int i=0;i<16;i++){
    int s = i*4 + r4;
    out[(size_t)(t*64+s)*64 + c] = tile[c][s];
  }
}

extern "C" void kernel_launch(void* const* d_in, const int* in_sizes, int n_in,
                              void* d_out, int out_size, void* d_ws, size_t ws_size,
                              hipStream_t stream) {
  (void)in_sizes; (void)n_in; (void)out_size;
  const float* v1      = (const float*)d_in[0];
  const float* v2      = (const float*)d_in[1];
  const float* mem     = (const float*)d_in[2];
  const float* mt_w1   = (const float*)d_in[3];
  const float* mt_b1   = (const float*)d_in[4];
  const float* mt_w2   = (const float*)d_in[5];
  const float* mt_b2   = (const float*)d_in[6];
  const float* mt_wv   = (const float*)d_in[7];
  const float* mt_bv   = (const float*)d_in[8];
  const float* mts_w1  = (const float*)d_in[9];
  const float* mts_b1  = (const float*)d_in[10];
  const float* mts_w2  = (const float*)d_in[11];
  const float* mts_b2  = (const float*)d_in[12];
  const float* mts_wv  = (const float*)d_in[13];
  const float* mts_bv  = (const float*)d_in[14];
  const float* ht_w    = (const float*)d_in[15];
  const float* ht_b    = (const float*)d_in[16];
  const float* hts_w   = (const float*)d_in[17];
  const float* hts_b   = (const float*)d_in[18];
  const int*   y       = (const int*)d_in[19];
  const int*   idx     = (const int*)d_in[20];
  float* out = (float*)d_out;
  float* outmem = out + 262144;
  char* ws = (char*)d_ws;

  u16* w2a = (u16*)(ws + 0);
  u16* w2b = (u16*)(ws + 65536);
  u16* wc1 = (u16*)(ws + 131072);
  u16* wc2 = (u16*)(ws + 196608);
  float* c1   = (float*)(ws + 262144);
  float* c2   = (float*)(ws + 294912);
  float* bc1  = (float*)(ws + 327680);
  float* bc2  = (float*)(ws + 328192);
  float* wss  = (float*)(ws + 393216);   // 64*4096 f32 = 1MB

  const size_t PLANES_OFF = 2097152;
  const size_t PLANES_BYTES = (size_t)12800000 * 2 * 2;   // 51.2MB
  const bool bigws = ws_size >= PLANES_OFF + PLANES_BYTES;
  u16 *mh, *ml;
  if (bigws){ mh = (u16*)(ws + PLANES_OFF); }
  else      { mh = (u16*)outmem; }            // park planes in new_memory region
  ml = mh + 12800000;

  // 1. split bank to hi/lo planes (+ fused copy when planes don't alias outmem)
  split_copy_kernel<<<2048, 256, 0, stream>>>((const float4*)mem, (float4*)outmem,
                                              (u16x4*)mh, (u16x4*)ml, 3200000, bigws ? 1 : 0);
  // 2. weights/c/bc prep
  prep_kernel<<<512, 128, 0, stream>>>(v1, v2,
      mt_w1, mt_b1, mt_w2, mt_b2, mt_wv, mt_bv,
      mts_w1, mts_b1, mts_w2, mts_b2, mts_wv, mts_bv,
      ht_w, ht_b, hts_w, hts_b,
      w2a, w2b, wc1, wc2, c1, c2, bc1, bc2);
  // 3. main fused compute -> wss
  main_kernel<<<dim3(64, 64), 256, 0, stream>>>(mh, ml, idx,
      w2a, w2b, wc1, wc2, c1, c2, bc1, bc2, wss);
  // 4. new_memory
  if (!bigws)
    copy_kernel<<<2048, 256, 0, stream>>>((const float4*)mem, (float4*)outmem, 3200000);
  update_kernel<<<64, 128, 0, stream>>>(mem, v2, y, outmem);
  // 5. scores transpose into out
  transpose_kernel<<<64, 256, 0, stream>>>(wss, out);
}